// Round 1
// baseline (184.403 us; speedup 1.0000x reference)
//
#include <hip/hip_runtime.h>

// NPZD plankton ODE: B*WK = 106496 independent trajectories, 56 Euler steps.
//
// R7: counters showed VGPR_Count=48 (compiler clamped the "18 loads in
// flight" staging down to a serialized trickle) and Occupancy 23% (wall
// time dominated by single-wave integrate + load drain, strictly
// serialized per block). Restructure:
//  - 2 batches per block, software-pipelined: waves 1-3 ISSUE batch i+1's
//    row loads into registers, wave 0 integrates batch i from LDS while
//    the loads are in flight; compact after the barrier.
//  - __launch_bounds__(256,4): authorize 128 VGPR so the 24 staged float4
//    per staging thread genuinely stay in registers / in flight.
//  - 12-word-group compaction: words {0,3,6,9} of each 3-float4 group are
//    the needed stride-3 samples (j = 4g..4g+3, week = g/14 never splits
//    a group since 56 % 4 == 0) -> ONE aligned ds_write_b128 per array per
//    group. Same LDS image as R6 (stride-60 weeks), integrate untouched.
//  - plain (cached) loads instead of nontemporal: input (143 MB) fits L3;
//    let repeat dispatches hit it.

typedef float f32x4 __attribute__((ext_vector_type(4)));

#define NPZD_B 2048
#define NPZD_WK 52
#define NPZD_HRS 8760
#define NPZD_WSTRIDE 60        // padded words per week (16B-aligned)
#define NPZD_LDSW (NPZD_WK * NPZD_WSTRIDE + 16)   // 3136
#define NPZD_NGRP 728          // 12-word groups; covers j = 0..2911 exactly
#define NPZD_BPB 2             // batches per block

__global__ __launch_bounds__(256, 4) void npzd_kernel(
    const float* __restrict__ X_in,     // (B, WK, 5, 1)
    const float* __restrict__ gf,       // (B, HRS)
    const float* __restrict__ gm,       // (B, HRS)
    const float* __restrict__ params,   // (B, 10)
    const float* __restrict__ dt_ptr,   // scalar
    float* __restrict__ out)            // (B, WK, 4, 8)
{
    __shared__ __align__(16) float lds_f[NPZD_LDSW];
    __shared__ __align__(16) float lds_m[NPZD_LDSW];

    const int tid = threadIdx.x;
    const int b0  = blockIdx.x * NPZD_BPB;
    const float dt = dt_ptr[0];   // 0.125

    // Staged registers for one row (waves 1-3 only: 192 threads x 4 groups).
    // 4 groups x 3 float4 x 2 arrays = 24 f4 = 96 VGPRs held across the
    // integrate phase -- this is the in-flight window that hides HBM/L3
    // latency under the serial ODE chain.
    f32x4 sf[4][3], sm[4][3];
    int gg[4];

    #pragma unroll
    for (int it = 0; it <= NPZD_BPB; ++it) {
        // ---- A: issue batch `it` row loads (waves 1-3), keep in regs ----
        if (it < NPZD_BPB && tid >= 64) {
            const f32x4* __restrict__ gf4 = (const f32x4*)(gf + (size_t)(b0 + it) * NPZD_HRS);
            const f32x4* __restrict__ gm4 = (const f32x4*)(gm + (size_t)(b0 + it) * NPZD_HRS);
            #pragma unroll
            for (int i = 0; i < 4; ++i) {
                int g = (tid - 64) + 192 * i;
                if (g >= NPZD_NGRP) g = NPZD_NGRP - 1;   // dup load+write, benign
                gg[i] = g;
                #pragma unroll
                for (int c = 0; c < 3; ++c) {
                    sf[i][c] = gf4[3 * g + c];
                    sm[i][c] = gm4[3 * g + c];
                }
            }
        }

        // ---- B: integrate batch `it-1` from LDS (wave 0, lanes 0..51),
        //         while batch `it`'s loads are in flight ----
        if (it > 0 && tid < NPZD_WK) {
            const int b = b0 + it - 1;
            const int w = tid;

            const float* xb = X_in + ((size_t)b * NPZD_WK + w) * 5;
            float N = xb[1], P = xb[2], Z = xb[3], D = xb[4];

            const float* pp = params + (size_t)b * 10;   // block-uniform -> s_load
            const float chi   = pp[0];
            const float rho2  = pp[1] * 2.0f;
            const float gam1  = pp[2] * 0.1f;
            const float lam05 = pp[3] * 0.05f;
            const float eps1  = pp[4] * 0.1f;
            const float alp3  = pp[5] * 0.3f;
            const float bet6  = pp[6] * 0.6f;
            const float eta15 = pp[7] * 0.15f;
            const float phi4  = pp[8] * 0.4f;
            const float zet1  = pp[9] * 0.1f;
            const float rem   = 1.0f - alp3 - bet6;

            float oN[8], oP[8], oZ[8], oD[8];
            oN[0] = N; oP[0] = P; oZ[0] = Z; oD[0] = D;

            const float* lf = lds_f + w * NPZD_WSTRIDE;
            const float* lm = lds_m + w * NPZD_WSTRIDE;

            #pragma unroll
            for (int g14 = 0; g14 < 14; ++g14) {
                // one aligned ds_read_b128 per array per 4 steps
                const f32x4 f4 = *(const f32x4*)(lf + 4 * g14);
                const f32x4 m4 = *(const f32x4*)(lm + 4 * g14);
                const float fs[4] = {f4.x, f4.y, f4.z, f4.w};
                const float ms[4] = {m4.x, m4.y, m4.z, m4.w};
                #pragma unroll
                for (int q = 0; q < 4; ++q) {
                    const float ft = fs[q], mt = ms[q];
                    const float Pc = fmaxf(0.01f, P);
                    const float Zc = fmaxf(0.01f, Z);
                    const float gN = N * __builtin_amdgcn_rcpf(chi + N);
                    const float zg = rho2 * (1.0f - __expf(-lam05 * Pc)) * Zc;
                    const float up = gN * ft * Pc;
                    const float Nn = N + dt * (-up + alp3 * zg + eps1 * P + gam1 * Z + phi4 * D + mt * (8.0f - N));
                    const float Pn = P + dt * (up - zg - eps1 * P - eta15 * P - mt * P);
                    const float Zn = Z + dt * (bet6 * zg - gam1 * Z - mt * Z);
                    const float Dn = D + dt * (eta15 * P + rem * zg - phi4 * D - zet1 * D - mt * D);
                    N = Nn; P = Pn; Z = Zn; D = Dn;
                }
                if (g14 & 1) {   // after steps 7,15,...,55
                    const int c = (g14 >> 1) + 1;
                    oN[c] = N; oP[c] = P; oZ[c] = Z; oD[c] = D;
                }
            }

            // Output: (b, w, state, 8) -> 32 contiguous floats per trajectory.
            f32x4* o4 = (f32x4*)(out + ((size_t)b * NPZD_WK + w) * 32);
            o4[0] = (f32x4){oN[0], oN[1], oN[2], oN[3]};
            o4[1] = (f32x4){oN[4], oN[5], oN[6], oN[7]};
            o4[2] = (f32x4){oP[0], oP[1], oP[2], oP[3]};
            o4[3] = (f32x4){oP[4], oP[5], oP[6], oP[7]};
            o4[4] = (f32x4){oZ[0], oZ[1], oZ[2], oZ[3]};
            o4[5] = (f32x4){oZ[4], oZ[5], oZ[6], oZ[7]};
            o4[6] = (f32x4){oD[0], oD[1], oD[2], oD[3]};
            o4[7] = (f32x4){oD[4], oD[5], oD[6], oD[7]};
        }
        __syncthreads();   // wave 0 done reading LDS; safe to overwrite

        // ---- C: compact the in-flight row into LDS ----
        // Group g = words 12g..12g+11; needed words 12g+{0,3,6,9} =
        // (f4_0.x, f4_0.w, f4_1.z, f4_2.y) -> j = 4g..4g+3, all in week
        // w = g/14 (56 % 4 == 0 -> no group straddles a week), dest
        // p0 = 4g + 4w, 16B-aligned: ONE ds_write_b128 per array.
        if (it < NPZD_BPB && tid >= 64) {
            #pragma unroll
            for (int i = 0; i < 4; ++i) {
                const int g  = gg[i];
                const int w  = (g * 9363) >> 17;   // g/14, exact for g <= 729
                const int p0 = 4 * g + 4 * w;
                *(f32x4*)(lds_f + p0) = (f32x4){sf[i][0].x, sf[i][0].w, sf[i][1].z, sf[i][2].y};
                *(f32x4*)(lds_m + p0) = (f32x4){sm[i][0].x, sm[i][0].w, sm[i][1].z, sm[i][2].y};
            }
        }
        __syncthreads();   // LDS ready for next iteration's integrate
    }
}

extern "C" void kernel_launch(void* const* d_in, const int* in_sizes, int n_in,
                              void* d_out, int out_size, void* d_ws, size_t ws_size,
                              hipStream_t stream) {
    const float* X_in   = (const float*)d_in[0];
    const float* gf     = (const float*)d_in[1];
    const float* gm     = (const float*)d_in[2];
    const float* params = (const float*)d_in[3];
    const float* dt_ptr = (const float*)d_in[4];
    float* out = (float*)d_out;

    npzd_kernel<<<NPZD_B / NPZD_BPB, 256, 0, stream>>>(X_in, gf, gm, params, dt_ptr, out);
}

// Round 2
// 182.758 us; speedup vs baseline: 1.0090x; 1.0090x over previous
//
#include <hip/hip_runtime.h>

// NPZD plankton ODE: B*WK = 106496 independent trajectories, 56 Euler steps.
//
// R8: the R2-R7 invariant (63-69 us regardless of load structure) is a
// DUTY-CYCLE limit, not a load-structure limit: per block, stage ->
// barrier -> integrate serializes, the block holds its LDS slot through
// the ~1.3 us integrate, no successor launches, and the memory pipe idles
// ~70% of each block's lifetime (0.3 duty x 6.3 TB/s ~= 1.9 TB/s ~= the
// measured 1.1-1.4). R7's register-pipeline fix was silently destroyed by
// the compiler (VGPR_Count=64 < the 96 needed -> loads sunk past the
// barrier).
// Fix: ONE WAVE PER BLOCK, one batch per wave, ZERO cross-wave coupling.
// Each wave stages its own row (coalesced f4, 18 loads in flight per
// pass - nothing lives across a barrier so the allocator can't refuse),
// compacts into its own LDS (R6's proven stride-60 layout + magic-div),
// integrates lanes 0..51. 25 KB LDS -> 6 independent wave-blocks per CU;
// waves desync naturally, so staging of some overlaps integrate of
// others and memory stays busy end-to-end.

typedef float f32x4 __attribute__((ext_vector_type(4)));

#define NPZD_B 2048
#define NPZD_WK 52
#define NPZD_HRS 8760
#define NPZD_NF4 2190          // 8760/4 float4 per row
#define NPZD_WSTRIDE 60        // padded words per week (16B-aligned)
#define NPZD_LDSW (NPZD_WK * NPZD_WSTRIDE + 16)   // 3136; p max 3127

__global__ __launch_bounds__(64, 4) void npzd_kernel(
    const float* __restrict__ X_in,     // (B, WK, 5, 1)
    const float* __restrict__ gf,       // (B, HRS)
    const float* __restrict__ gm,       // (B, HRS)
    const float* __restrict__ params,   // (B, 10)
    const float* __restrict__ dt_ptr,   // scalar
    float* __restrict__ out)            // (B, WK, 4, 8)
{
    __shared__ __align__(16) float lds_f[NPZD_LDSW];
    __shared__ __align__(16) float lds_m[NPZD_LDSW];

    const int b    = blockIdx.x;
    const int lane = threadIdx.x;

    // ---- hoisted independent loads: in flight under the staging ----
    const float dt = dt_ptr[0];   // 0.125
    const int wc = (lane < NPZD_WK) ? lane : (NPZD_WK - 1);   // OOB-safe
    const float* xb = X_in + ((size_t)b * NPZD_WK + wc) * 5;
    const float x1 = xb[1], x2 = xb[2], x3 = xb[3], x4 = xb[4];

    const float* pp = params + (size_t)b * 10;   // block-uniform -> s_load
    const float chi   = pp[0];
    const float rho2  = pp[1] * 2.0f;
    const float gam1  = pp[2] * 0.1f;
    const float lam05 = pp[3] * 0.05f;
    const float eps1  = pp[4] * 0.1f;
    const float alp3  = pp[5] * 0.3f;
    const float bet6  = pp[6] * 0.6f;
    const float eta15 = pp[7] * 0.15f;
    const float phi4  = pp[8] * 0.4f;
    const float zet1  = pp[9] * 0.1f;
    const float rem   = 1.0f - alp3 - bet6;

    const f32x4* __restrict__ gf4 = (const f32x4*)(gf + (size_t)b * NPZD_HRS);
    const f32x4* __restrict__ gm4 = (const f32x4*)(gm + (size_t)b * NPZD_HRS);

    // ---- stage + compact: 4 passes x 9 float4 per lane (covers 2304 >= 2190)
    // 18 loads in flight per pass (72 VGPRs live, no barrier in between).
    #pragma unroll
    for (int pass = 0; pass < 4; ++pass) {
        f32x4 fv[9], mv[9];
        int kk[9];
        #pragma unroll
        for (int c = 0; c < 9; ++c) {
            int k = (pass * 9 + c) * 64 + lane;
            if (k >= NPZD_NF4) k = NPZD_NF4 - 1;   // dup load+dup write, benign
            kk[c] = k;
            fv[c] = gf4[k];
            mv[c] = gm4[k];
        }
        // float4 k covers h = 4k..4k+3. h%3==0 at e0=(3-k%3)%3 (and e0+3 if
        // k%3==0). j = h/3; dest p = j + 4*(j/56); (j*9363)>>19 == j/56 for
        // j <= 2919. Same image as R6 (verified).
        #pragma unroll
        for (int c = 0; c < 9; ++c) {
            const int k = kk[c];
            const float fe[4] = {fv[c].x, fv[c].y, fv[c].z, fv[c].w};
            const float me[4] = {mv[c].x, mv[c].y, mv[c].z, mv[c].w};
            const int rm = k % 3;
            const int e0 = (rm == 0) ? 0 : (3 - rm);
            const int j0 = (4 * k + e0) / 3;
            const int p0 = j0 + 4 * ((j0 * 9363) >> 19);
            lds_f[p0] = fe[e0];
            lds_m[p0] = me[e0];
            if (rm == 0) {               // second multiple of 3 (e=3)
                const int j1 = j0 + 1;
                const int p1 = j1 + 4 * ((j1 * 9363) >> 19);
                lds_f[p1] = fe[3];
                lds_m[p1] = me[3];
            }
        }
    }
    __syncthreads();   // single-wave barrier: just drains lgkmcnt, ~free

    // ---- integrate: lanes 0..51, one trajectory each, from own LDS ----
    if (lane >= NPZD_WK) return;
    const int w = lane;

    float N = x1, P = x2, Z = x3, D = x4;

    float oN[8], oP[8], oZ[8], oD[8];
    oN[0] = N; oP[0] = P; oZ[0] = Z; oD[0] = D;

    const float* lf = lds_f + w * NPZD_WSTRIDE;
    const float* lm = lds_m + w * NPZD_WSTRIDE;

    #pragma unroll
    for (int g = 0; g < 14; ++g) {
        // one aligned ds_read_b128 per array per 4 steps
        const f32x4 f4 = *(const f32x4*)(lf + 4 * g);
        const f32x4 m4 = *(const f32x4*)(lm + 4 * g);
        const float fs[4] = {f4.x, f4.y, f4.z, f4.w};
        const float ms[4] = {m4.x, m4.y, m4.z, m4.w};
        #pragma unroll
        for (int q = 0; q < 4; ++q) {
            const float ft = fs[q], mt = ms[q];
            const float Pc = fmaxf(0.01f, P);
            const float Zc = fmaxf(0.01f, Z);
            const float gN = N * __builtin_amdgcn_rcpf(chi + N);
            const float zg = rho2 * (1.0f - __expf(-lam05 * Pc)) * Zc;
            const float up = gN * ft * Pc;
            const float Nn = N + dt * (-up + alp3 * zg + eps1 * P + gam1 * Z + phi4 * D + mt * (8.0f - N));
            const float Pn = P + dt * (up - zg - eps1 * P - eta15 * P - mt * P);
            const float Zn = Z + dt * (bet6 * zg - gam1 * Z - mt * Z);
            const float Dn = D + dt * (eta15 * P + rem * zg - phi4 * D - zet1 * D - mt * D);
            N = Nn; P = Pn; Z = Zn; D = Dn;
        }
        if (g & 1) {   // after steps 7,15,...,55
            const int c = (g >> 1) + 1;
            oN[c] = N; oP[c] = P; oZ[c] = Z; oD[c] = D;
        }
    }

    // Output: (b, w, state, 8) -> 32 contiguous floats per trajectory.
    f32x4* o4 = (f32x4*)(out + ((size_t)b * NPZD_WK + w) * 32);
    o4[0] = (f32x4){oN[0], oN[1], oN[2], oN[3]};
    o4[1] = (f32x4){oN[4], oN[5], oN[6], oN[7]};
    o4[2] = (f32x4){oP[0], oP[1], oP[2], oP[3]};
    o4[3] = (f32x4){oP[4], oP[5], oP[6], oP[7]};
    o4[4] = (f32x4){oZ[0], oZ[1], oZ[2], oZ[3]};
    o4[5] = (f32x4){oZ[4], oZ[5], oZ[6], oZ[7]};
    o4[6] = (f32x4){oD[0], oD[1], oD[2], oD[3]};
    o4[7] = (f32x4){oD[4], oD[5], oD[6], oD[7]};
}

extern "C" void kernel_launch(void* const* d_in, const int* in_sizes, int n_in,
                              void* d_out, int out_size, void* d_ws, size_t ws_size,
                              hipStream_t stream) {
    const float* X_in   = (const float*)d_in[0];
    const float* gf     = (const float*)d_in[1];
    const float* gm     = (const float*)d_in[2];
    const float* params = (const float*)d_in[3];
    const float* dt_ptr = (const float*)d_in[4];
    float* out = (float*)d_out;

    npzd_kernel<<<NPZD_B, 64, 0, stream>>>(X_in, gf, gm, params, dt_ptr, out);
}